// Round 6
// baseline (136.275 us; speedup 1.0000x reference)
//
#include <hip/hip_runtime.h>
#include <cmath>

constexpr int   DIM   = 2048;
constexpr int   NEXP  = 4;
constexpr float EPS   = 1e-6f;
constexpr float SCALE = 3.0f;

typedef float f32x4 __attribute__((ext_vector_type(4)));

// Prologue: fuse fw[e][d] = rw[e][d] * nw[d] into d_ws (32 KiB).
__global__ void fuse_weights_kernel(const float* __restrict__ nw,
                                    const float* __restrict__ rw,
                                    float* __restrict__ fw)
{
    const int i = blockIdx.x * blockDim.x + threadIdx.x;  // f32x4 index
    if (i < NEXP * DIM / 4) {
        const f32x4 r = reinterpret_cast<const f32x4*>(rw)[i];
        const f32x4 n = reinterpret_cast<const f32x4*>(nw)[i & (DIM / 4 - 1)];
        reinterpret_cast<f32x4*>(fw)[i] = r * n;
    }
}

// Main: one wave per QUAD of rows, grid-strided (R1's proven mapping).
// Weights are NOT register-resident: fw is re-loaded from d_ws each k-chunk
// (L1/L2-hot 32 KiB, vmcnt pipe -- no lgkm serialization like R2's LDS).
// This frees ~128 VGPR -> >=4 waves/SIMD (2x the waves of R1..R5), and fw
// loads amortize over 4 rows so extra cache traffic == 1x the x traffic.
__global__ __launch_bounds__(256, 4)
void altup_router_kernel(const float* __restrict__ x,
                         const float* __restrict__ fw,
                         float* __restrict__ out,
                         int nrows)
{
    const int tid    = threadIdx.x;
    const int lane   = tid & 63;
    const int wid    = tid >> 6;
    const int nwaves = gridDim.x * (blockDim.x >> 6);
    const int wave   = blockIdx.x * (blockDim.x >> 6) + wid;
    const int base   = lane * 4;  // float offset inside each 256-float chunk

    const int nquads = (nrows + 3) >> 2;

    for (int q = wave; q < nquads; q += nwaves) {
        const int row0 = q * 4;

        // Clamp tail rows to last valid row (loads harmless, stores guarded).
        const float* xr[4];
#pragma unroll
        for (int r = 0; r < 4; ++r) {
            int rr = row0 + r;
            if (rr > nrows - 1) rr = nrows - 1;
            xr[r] = x + (size_t)rr * DIM;
        }

        float acc[4][5];  // per row: sumsq, dot0..3
#pragma unroll
        for (int r = 0; r < 4; ++r)
#pragma unroll
            for (int i = 0; i < 5; ++i) acc[r][i] = 0.f;

#pragma unroll
        for (int k = 0; k < 8; ++k) {
            const int d = k * 256 + base;

            // 4 cached weight loads (L1-hot) + 4 streaming x loads per chunk.
            f32x4 wv[NEXP];
#pragma unroll
            for (int e = 0; e < NEXP; ++e)
                wv[e] = *reinterpret_cast<const f32x4*>(fw + e * DIM + d);

            f32x4 xv[4];
#pragma unroll
            for (int r = 0; r < 4; ++r)
                xv[r] = __builtin_nontemporal_load(
                            reinterpret_cast<const f32x4*>(xr[r] + d));

#pragma unroll
            for (int r = 0; r < 4; ++r) {
                const f32x4 a = xv[r];
#pragma unroll
                for (int j = 0; j < 4; ++j)
                    acc[r][0] = fmaf(a[j], a[j], acc[r][0]);
#pragma unroll
                for (int e = 0; e < NEXP; ++e) {
                    const f32x4 we = wv[e];
#pragma unroll
                    for (int j = 0; j < 4; ++j)
                        acc[r][1 + e] = fmaf(a[j], we[j], acc[r][1 + e]);
                }
            }
        }

        // One 64-lane butterfly for all 20 partials (30 shuffle-adds / row,
        // same per-row cost as R1).
#pragma unroll
        for (int m = 32; m >= 1; m >>= 1) {
#pragma unroll
            for (int r = 0; r < 4; ++r)
#pragma unroll
                for (int i = 0; i < 5; ++i)
                    acc[r][i] += __shfl_xor(acc[r][i], m, 64);
        }

        if (lane == 0) {
#pragma unroll
            for (int r = 0; r < 4; ++r) {
                const int rr = row0 + r;
                if (rr < nrows) {
                    const float ir = rsqrtf(acc[r][0] * (1.0f / DIM) + EPS);
                    f32x4 o;
                    o.x = tanhf(acc[r][1] * ir * SCALE);
                    o.y = tanhf(acc[r][2] * ir * SCALE);
                    o.z = tanhf(acc[r][3] * ir * SCALE);
                    o.w = tanhf(acc[r][4] * ir * SCALE);
                    *reinterpret_cast<f32x4*>(out + (size_t)rr * 4) = o;
                }
            }
        }
    }
}

extern "C" void kernel_launch(void* const* d_in, const int* in_sizes, int n_in,
                              void* d_out, int out_size, void* d_ws, size_t ws_size,
                              hipStream_t stream)
{
    const float* x   = (const float*)d_in[0];  // (4, 8192, 2048) f32
    const float* nw  = (const float*)d_in[1];  // (2048,) f32
    const float* rw  = (const float*)d_in[2];  // (4, 2048) f32
    float*       out = (float*)d_out;          // (4, 8192, 4) f32
    float*       fw  = (float*)d_ws;           // (4, 2048) fused weights

    const int nrows = in_sizes[0] / DIM;       // 32768

    // Prologue: 2048 f32x4 elements -> 8 blocks x 256 threads.
    hipLaunchKernelGGL(fuse_weights_kernel, dim3(8), dim3(256), 0, stream,
                       nw, rw, fw);

    const int nquads = (nrows + 3) >> 2;       // 8192

    // 512 blocks x 4 waves = 2048 waves, grid-striding ~4 quads each.
    int blocks = 512;
    const int max_blocks = (nquads + 3) / 4;
    if (blocks > max_blocks) blocks = max_blocks;
    if (blocks < 1) blocks = 1;

    hipLaunchKernelGGL(altup_router_kernel, dim3(blocks), dim3(256), 0, stream,
                       x, fw, out, nrows);
}

// Round 7
// 49.259 us; speedup vs baseline: 2.7665x; 2.7665x over previous
//
#include <hip/hip_runtime.h>
#include <cmath>

constexpr int   DIM   = 2048;
constexpr int   NEXP  = 4;
constexpr float EPS   = 1e-6f;
constexpr float SCALE = 3.0f;

// R1 structure (best measured: 49.3 us = 5.33 TB/s read-only).
// One wave (64 lanes) per row, grid-strided. Each lane covers 32 elements
// (8 x float4 at d = k*256 + lane*4). Fused router weight rw[e][d]*nw[d]
// is REGISTER-resident (128 VGPR) -- R2 (LDS) and R6 (global/L2) both put
// weight-load latency on the FMA critical path and regressed 2.4-2.7x.
// 5 partials (sumsq + 4 dots) reduced with a 64-lane xor-shuffle butterfly;
// lane 0 does 4 tanh and one float4 store.
__global__ __launch_bounds__(256, 2)
void altup_router_kernel(const float* __restrict__ x,
                         const float* __restrict__ nw,
                         const float* __restrict__ rw,
                         float* __restrict__ out,
                         int nrows)
{
    const int lane          = threadIdx.x & 63;
    const int wid_in_blk    = threadIdx.x >> 6;
    const int waves_per_blk = blockDim.x >> 6;
    const int nwaves        = gridDim.x * waves_per_blk;
    const int wave          = blockIdx.x * waves_per_blk + wid_in_blk;

    const int base = lane * 4;  // float offset inside each 256-float chunk

    // Preload fused weights: w[e][k] = rw[e*DIM + d] * nw[d]
    float4 w[NEXP][8];
#pragma unroll
    for (int e = 0; e < NEXP; ++e) {
#pragma unroll
        for (int k = 0; k < 8; ++k) {
            const int d = k * 256 + base;
            const float4 r = *reinterpret_cast<const float4*>(rw + e * DIM + d);
            const float4 n = *reinterpret_cast<const float4*>(nw + d);
            w[e][k] = make_float4(r.x * n.x, r.y * n.y, r.z * n.z, r.w * n.w);
        }
    }

    for (int row = wave; row < nrows; row += nwaves) {
        const float* xr = x + (size_t)row * DIM;

        float acc[5] = {0.f, 0.f, 0.f, 0.f, 0.f};  // sumsq, dot0..3
#pragma unroll
        for (int k = 0; k < 8; ++k) {
            const float4 xv = *reinterpret_cast<const float4*>(xr + k * 256 + base);

            acc[0] = fmaf(xv.x, xv.x, acc[0]);
            acc[0] = fmaf(xv.y, xv.y, acc[0]);
            acc[0] = fmaf(xv.z, xv.z, acc[0]);
            acc[0] = fmaf(xv.w, xv.w, acc[0]);
#pragma unroll
            for (int e = 0; e < NEXP; ++e) {
                acc[1 + e] = fmaf(xv.x, w[e][k].x, acc[1 + e]);
                acc[1 + e] = fmaf(xv.y, w[e][k].y, acc[1 + e]);
                acc[1 + e] = fmaf(xv.z, w[e][k].z, acc[1 + e]);
                acc[1 + e] = fmaf(xv.w, w[e][k].w, acc[1 + e]);
            }
        }

        // 64-lane butterfly reduction of the 5 partials
#pragma unroll
        for (int m = 32; m >= 1; m >>= 1) {
#pragma unroll
            for (int i = 0; i < 5; ++i)
                acc[i] += __shfl_xor(acc[i], m, 64);
        }

        if (lane == 0) {
            const float inv_rms = rsqrtf(acc[0] * (1.0f / DIM) + EPS);
            float4 o;
            o.x = tanhf(acc[1] * inv_rms * SCALE);
            o.y = tanhf(acc[2] * inv_rms * SCALE);
            o.z = tanhf(acc[3] * inv_rms * SCALE);
            o.w = tanhf(acc[4] * inv_rms * SCALE);
            reinterpret_cast<float4*>(out)[row] = o;
        }
    }
}

extern "C" void kernel_launch(void* const* d_in, const int* in_sizes, int n_in,
                              void* d_out, int out_size, void* d_ws, size_t ws_size,
                              hipStream_t stream)
{
    const float* x   = (const float*)d_in[0];  // (4, 8192, 2048) f32
    const float* nw  = (const float*)d_in[1];  // (2048,) f32
    const float* rw  = (const float*)d_in[2];  // (4, 2048) f32
    float*       out = (float*)d_out;          // (4, 8192, 4) f32

    const int nrows = in_sizes[0] / DIM;       // 32768

    // Target ~8 rows per wave; cap at 1024 blocks (4 waves each).
    int waves_needed  = (nrows + 7) / 8;
    int blocks        = (waves_needed + 3) / 4;
    if (blocks > 1024) blocks = 1024;
    if (blocks < 1)    blocks = 1;

    hipLaunchKernelGGL(altup_router_kernel, dim3(blocks), dim3(256), 0, stream,
                       x, nw, rw, out, nrows);
}